// Round 7
// baseline (126.993 us; speedup 1.0000x reference)
//
#include <hip/hip_runtime.h>
#include <cmath>

#define IMG_H 512
#define IMG_W 512
#define TH 16            // tile rows (output) -- halved for occupancy: LDS 26.6KB -> 6 blocks/CU
#define TW 64            // tile cols (output)
#define LDSW 83          // ODD element stride (coprime with banks; b64 pair-index covers all 16 pairs)
#define NPLANES 96       // 32 batch * 3 channels
#define NPIX 25165824.0  // 96*512*512

typedef float vf2 __attribute__((ext_vector_type(2)));

struct GaussW { float w[11]; };

__global__ __launch_bounds__(256, 6) void ssim_main(
    const float* __restrict__ img1, const float* __restrict__ img2,
    float* __restrict__ partials, GaussW gw, int use_atomic, float* __restrict__ out)
{
    // Interleaved pair layout: (A,B) and (P,Q) share weights -> v_pk_fma_f32.
    __shared__ vf2   VAB[TH][LDSW];   // 10624 B
    __shared__ vf2   VPQ[TH][LDSW];   // 10624 B
    __shared__ float VS [TH][LDSW];   //  5312 B   (total ~26.6 KB -> 6 blocks/CU, 24 waves)
    __shared__ float wsum[4];

    const int tid = threadIdx.x;
    const int plane = blockIdx.z;
    const int tr0 = blockIdx.y * TH;
    const int tc0 = blockIdx.x * TW;
    const float* __restrict__ plane1 = img1 + ((size_t)plane << 18);  // uniform -> SGPR base
    const float* __restrict__ plane2 = img2 + ((size_t)plane << 18);

    // ---------------- Phase 1: vertical conv, packed accumulator scatter ------
    // 160 active threads: one lds column j each, 2 chunks x 8 output rows.
    // 18 input rows per chunk, first-touch accumulator init, single code path
    // (round-4 lesson: interior/edge dual path demotes accumulators to scratch).
    {
        const int j = tid % 80;       // lds col
        const int chunk = tid / 80;   // 0..1 active; tid>=160 idle in phase 1
        if (chunk < 2) {
            const int r0 = chunk * 8;
            const int gc = tc0 + j - 8;
            const float cmask = (gc >= 0 && gc < IMG_W) ? 1.f : 0.f;
            const int gcc = min(max(gc, 0), IMG_W - 1);   // v_med3

            vf2 aAB[8], aPQ[8];       // 40 acc dwords (was 55 at TH=32) -> VGPR <= 64
            float aS[8];

            #pragma unroll
            for (int ii = 0; ii < 18; ++ii) {             // input rows r0-5 .. r0+12
                const int gr = tr0 + r0 - 5 + ii;
                const float rmask = (gr >= 0 && gr < IMG_H) ? cmask : 0.f;
                const int grc = min(max(gr, 0), IMG_H - 1);
                const uint32_t idx = (uint32_t)(grc * IMG_W + gcc);
                const float a = plane1[idx] * rmask;
                const float b = plane2[idx] * rmask;
                const vf2 ab = { a, b };
                const vf2 pq = ab * ab;            // v_pk_mul_f32
                const float s = a * b;
                #pragma unroll
                for (int o = 0; o < 8; ++o) {
                    if (o <= ii && ii <= o + 10) {          // compile-time predicate
                        const float wt = gw.w[ii - o];
                        const vf2 wtv = { wt, wt };
                        if (ii == o) {                       // first touch
                            aAB[o] = wtv * ab;
                            aPQ[o] = wtv * pq;
                            aS[o]  = wt * s;
                        } else {
                            aAB[o] = __builtin_elementwise_fma(wtv, ab, aAB[o]);
                            aPQ[o] = __builtin_elementwise_fma(wtv, pq, aPQ[o]);
                            aS[o]  = fmaf(wt, s, aS[o]);
                        }
                    }
                }
            }
            #pragma unroll
            for (int o = 0; o < 8; ++o) {
                const int r = r0 + o;
                VAB[r][j] = aAB[o];        // ds_write_b64
                VPQ[r][j] = aPQ[o];        // ds_write_b64
                VS [r][j] = aS[o];         // ds_write_b32
            }
        }
    }
    __syncthreads();

    // ---------------- Phase 2: horizontal conv, packed per-column scatter -----
    // Row index in LOW lane bits (round-6 bank fix). 256 threads: 16 rows x
    // 16 col-groups of 4. Per half-wave, b64 pair = (3r+4cg+k) mod 16 covers
    // all 16 pairs x2 (free); b32 covers all banks <=2-way.
    float lsum = 0.f;
    {
        const int r = tid & 15;        // 0..15  (low bits!)
        const int c0 = (tid >> 4) * 4; // col group 0..15, 4 output cols each
        const vf2*   __restrict__ bAB = &VAB[r][c0];
        const vf2*   __restrict__ bPQ = &VPQ[r][c0];
        const float* __restrict__ bS  = &VS [r][c0];

        vf2 mAB[4], ePQ[4];
        float e12[4];

        #pragma unroll
        for (int k = 3; k <= 16; ++k) {          // window cols c0+3 .. c0+16
            const vf2   vab = bAB[k];
            const vf2   vpq = bPQ[k];
            const float vs  = bS[k];
            #pragma unroll
            for (int c = 0; c < 4; ++c) {
                if (k - 13 <= c && c <= k - 3) {            // compile-time
                    const float wt = gw.w[k - 3 - c];
                    const vf2 wtv = { wt, wt };
                    if (k == c + 3) {                        // first touch
                        mAB[c] = wtv * vab;
                        ePQ[c] = wtv * vpq;
                        e12[c] = wt * vs;
                    } else {
                        mAB[c] = __builtin_elementwise_fma(wtv, vab, mAB[c]);
                        ePQ[c] = __builtin_elementwise_fma(wtv, vpq, ePQ[c]);
                        e12[c] = fmaf(wt, vs, e12[c]);
                    }
                }
            }
        }
        #pragma unroll
        for (int c = 0; c < 4; ++c) {
            const float a1 = mAB[c].x, a2 = mAB[c].y;
            const float den1 = fmaf(a1, a1, fmaf(a2, a2, 0.0001f)); // mu11+mu22+C1
            const float s11  = fmaf(-a1, a1, ePQ[c].x);
            const float s22  = fmaf(-a2, a2, ePQ[c].y);
            const float s12  = fmaf(-a1, a2, e12[c]);
            const float mu12 = a1 * a2;
            const float num  = fmaf(2.f, mu12, 0.0001f) * fmaf(2.f, s12, 0.0009f);
            const float den  = den1 * (s11 + s22 + 0.0009f);
            lsum = fmaf(num, __builtin_amdgcn_rcpf(den), lsum);     // rcp ~1ulp, tol 2.7e-4
        }
    }
    // block reduction
    #pragma unroll
    for (int off = 32; off; off >>= 1) lsum += __shfl_down(lsum, off, 64);
    if ((tid & 63) == 0) wsum[tid >> 6] = lsum;
    __syncthreads();
    if (tid == 0) {
        const float bs = wsum[0] + wsum[1] + wsum[2] + wsum[3];
        if (use_atomic) {
            atomicAdd(out, bs * (float)(1.0 / NPIX));
        } else {
            const int bId = (blockIdx.z * gridDim.y + blockIdx.y) * gridDim.x + blockIdx.x;
            partials[bId] = bs;
        }
    }
}

__global__ __launch_bounds__(256) void ssim_reduce(
    const float* __restrict__ partials, int n, float* __restrict__ out)
{
    const int tid = threadIdx.x;
    double s = 0.0;
    for (int i = tid; i < n; i += 256) s += (double)partials[i];
    #pragma unroll
    for (int off = 32; off; off >>= 1) s += __shfl_down(s, off, 64);
    __shared__ double ws[4];
    if ((tid & 63) == 0) ws[tid >> 6] = s;
    __syncthreads();
    if (tid == 0) out[0] = (float)(((ws[0] + ws[1]) + (ws[2] + ws[3])) / NPIX);
}

extern "C" void kernel_launch(void* const* d_in, const int* in_sizes, int n_in,
                              void* d_out, int out_size, void* d_ws, size_t ws_size,
                              hipStream_t stream) {
    const float* img1 = (const float*)d_in[0];
    const float* img2 = (const float*)d_in[1];
    float* out = (float*)d_out;

    // Gaussian window (host, double precision, normalized)
    GaussW gw;
    {
        double g[11], sum = 0.0;
        for (int i = 0; i < 11; ++i) {
            const double c = (double)(i - 5);
            g[i] = std::exp(-(c * c) / 4.5);   // 2*sigma^2 = 4.5
            sum += g[i];
        }
        for (int i = 0; i < 11; ++i) gw.w[i] = (float)(g[i] / sum);
    }

    dim3 grid(IMG_W / TW, IMG_H / TH, NPLANES);   // 8 x 32 x 96 = 24576
    const int nPart = grid.x * grid.y * grid.z;

    if (ws_size >= (size_t)nPart * sizeof(float)) {
        // deterministic two-stage reduction
        ssim_main<<<grid, 256, 0, stream>>>(img1, img2, (float*)d_ws, gw, 0, out);
        ssim_reduce<<<1, 256, 0, stream>>>((float*)d_ws, nPart, out);
    } else {
        // fallback: atomic accumulation (still within tolerance)
        hipMemsetAsync(d_out, 0, sizeof(float), stream);
        ssim_main<<<grid, 256, 0, stream>>>(img1, img2, nullptr, gw, 1, out);
    }
}

// Round 8
// 112.951 us; speedup vs baseline: 1.1243x; 1.1243x over previous
//
#include <hip/hip_runtime.h>
#include <cmath>

#define IMG_H 512
#define IMG_W 512
#define TH 32            // tile rows (round-6 best base; TH=16 regressed: +19% issue)
#define TW 64            // tile cols
#define LDSW 83          // ODD element stride (b64 pair-index covers all 16 pairs per half-wave)
#define NPLANES 96       // 32 batch * 3 channels
#define NPIX 25165824.0  // 96*512*512

typedef float vf2 __attribute__((ext_vector_type(2)));

struct GaussW { float w[11]; };

// Force packed-fp32 math: VGPR_Count=68 across rounds 5-6 suggests
// __builtin_elementwise_fma may scalarize to 2x v_fma_f32. Pure (non-volatile)
// asm keeps scheduler freedom; "v" constraints give aligned VGPR pairs.
__device__ __forceinline__ vf2 pk_fma(vf2 a, vf2 b, vf2 c) {
    vf2 d;
    asm("v_pk_fma_f32 %0, %1, %2, %3" : "=v"(d) : "v"(a), "v"(b), "v"(c));
    return d;
}
__device__ __forceinline__ vf2 pk_mul(vf2 a, vf2 b) {
    vf2 d;
    asm("v_pk_mul_f32 %0, %1, %2" : "=v"(d) : "v"(a), "v"(b));
    return d;
}

__global__ __launch_bounds__(256, 3) void ssim_main(
    const float* __restrict__ img1, const float* __restrict__ img2,
    float* __restrict__ partials, GaussW gw, int use_atomic, float* __restrict__ out)
{
    // Interleaved pair layout: (A,B) and (P,Q) share weights -> v_pk_fma_f32.
    __shared__ vf2   VAB[TH][LDSW];   // 21248 B
    __shared__ vf2   VPQ[TH][LDSW];   // 21248 B
    __shared__ float VS [TH][LDSW];   // 10624 B   (total ~53 KB -> 3 blocks/CU)
    __shared__ float wsum[4];

    const int tid = threadIdx.x;
    const int plane = blockIdx.z;
    const int tr0 = blockIdx.y * TH;
    const int tc0 = blockIdx.x * TW;
    const float* __restrict__ plane1 = img1 + ((size_t)plane << 18);  // uniform -> SGPR base
    const float* __restrict__ plane2 = img2 + ((size_t)plane << 18);

    // ---------------- Phase 1: vertical conv, packed accumulator scatter ------
    // 240 threads: one lds column j each, 11 output rows (chunk r0 = {0,11,22}).
    // Single path (round-4 lesson: dual interior/edge path demotes accumulators
    // to scratch). First-touch init.
    {
        const int j = tid % 80;       // lds col
        const int chunk = tid / 80;   // 0..2 active; tid>=240 idle
        if (chunk < 3) {
            const int r0 = chunk * 11;
            const int gc = tc0 + j - 8;
            const float cmask = ((unsigned)gc < IMG_W) ? 1.f : 0.f;
            const int gcc = min(max(gc, 0), IMG_W - 1);   // v_med3

            vf2 aAB[11], aPQ[11];
            float aS[11];

            #pragma unroll
            for (int ii = 0; ii < 21; ++ii) {
                const int gr = tr0 + r0 - 5 + ii;
                const float rmask = ((unsigned)gr < IMG_H) ? cmask : 0.f;  // 1 unsigned cmp
                const int grc = min(max(gr, 0), IMG_H - 1);
                const uint32_t idx = (uint32_t)(grc * IMG_W + gcc);
                const float a = plane1[idx] * rmask;
                const float b = plane2[idx] * rmask;
                const vf2 ab = { a, b };
                const vf2 pq = pk_mul(ab, ab);
                const float s = a * b;
                #pragma unroll
                for (int o = 0; o < 11; ++o) {
                    if (o <= ii && ii <= o + 10) {          // compile-time predicate
                        const float wt = gw.w[ii - o];
                        const vf2 wtv = { wt, wt };
                        if (ii == o) {                       // first touch
                            aAB[o] = pk_mul(wtv, ab);
                            aPQ[o] = pk_mul(wtv, pq);
                            aS[o]  = wt * s;
                        } else {
                            aAB[o] = pk_fma(wtv, ab, aAB[o]);
                            aPQ[o] = pk_fma(wtv, pq, aPQ[o]);
                            aS[o]  = fmaf(wt, s, aS[o]);
                        }
                    }
                }
            }
            #pragma unroll
            for (int o = 0; o < 11; ++o) {
                const int r = r0 + o;
                if (r0 + o < TH) {   // only chunk2/o=10 is false
                    VAB[r][j] = aAB[o];        // ds_write_b64
                    VPQ[r][j] = aPQ[o];        // ds_write_b64
                    VS [r][j] = aS[o];         // ds_write_b32
                }
            }
        }
    }
    __syncthreads();

    // ---------------- Phase 2: horizontal conv, packed per-column scatter -----
    // Row index in LOW lane bits (round-6 bank fix): b64 pair (83r+8cg+k) mod 16
    // covers all 16 pairs x2 per half-wave; b32 covers all 32 banks x2 -> free.
    float lsum = 0.f;
    {
        const int r = tid & 31;        // 0..31  (low bits!)
        const int c0 = (tid >> 5) * 8; // col group 0..7
        const vf2*   __restrict__ bAB = &VAB[r][c0];
        const vf2*   __restrict__ bPQ = &VPQ[r][c0];
        const float* __restrict__ bS  = &VS [r][c0];

        vf2 mAB[8], ePQ[8];
        float e12[8];

        #pragma unroll
        for (int k = 3; k <= 20; ++k) {          // window cols c0+3 .. c0+20
            const vf2   vab = bAB[k];
            const vf2   vpq = bPQ[k];
            const float vs  = bS[k];
            #pragma unroll
            for (int c = 0; c < 8; ++c) {
                if (k - 13 <= c && c <= k - 3) {            // compile-time
                    const float wt = gw.w[k - 3 - c];
                    const vf2 wtv = { wt, wt };
                    if (k == c + 3) {                        // first touch
                        mAB[c] = pk_mul(wtv, vab);
                        ePQ[c] = pk_mul(wtv, vpq);
                        e12[c] = wt * vs;
                    } else {
                        mAB[c] = pk_fma(wtv, vab, mAB[c]);
                        ePQ[c] = pk_fma(wtv, vpq, ePQ[c]);
                        e12[c] = fmaf(wt, vs, e12[c]);
                    }
                }
            }
        }
        #pragma unroll
        for (int c = 0; c < 8; ++c) {
            const float a1 = mAB[c].x, a2 = mAB[c].y;
            const float den1 = fmaf(a1, a1, fmaf(a2, a2, 0.0001f)); // mu11+mu22+C1
            const float s11  = fmaf(-a1, a1, ePQ[c].x);
            const float s22  = fmaf(-a2, a2, ePQ[c].y);
            const float s12  = fmaf(-a1, a2, e12[c]);
            const float mu12 = a1 * a2;
            const float num  = fmaf(2.f, mu12, 0.0001f) * fmaf(2.f, s12, 0.0009f);
            const float den  = den1 * (s11 + s22 + 0.0009f);
            lsum = fmaf(num, __builtin_amdgcn_rcpf(den), lsum);     // rcp ~1ulp, tol 2.7e-4
        }
    }
    // block reduction
    #pragma unroll
    for (int off = 32; off; off >>= 1) lsum += __shfl_down(lsum, off, 64);
    if ((tid & 63) == 0) wsum[tid >> 6] = lsum;
    __syncthreads();
    if (tid == 0) {
        const float bs = wsum[0] + wsum[1] + wsum[2] + wsum[3];
        if (use_atomic) {
            atomicAdd(out, bs * (float)(1.0 / NPIX));
        } else {
            const int bId = (blockIdx.z * gridDim.y + blockIdx.y) * gridDim.x + blockIdx.x;
            partials[bId] = bs;
        }
    }
}

__global__ __launch_bounds__(256) void ssim_reduce(
    const float* __restrict__ partials, int n, float* __restrict__ out)
{
    const int tid = threadIdx.x;
    double s = 0.0;
    for (int i = tid; i < n; i += 256) s += (double)partials[i];
    #pragma unroll
    for (int off = 32; off; off >>= 1) s += __shfl_down(s, off, 64);
    __shared__ double ws[4];
    if ((tid & 63) == 0) ws[tid >> 6] = s;
    __syncthreads();
    if (tid == 0) out[0] = (float)(((ws[0] + ws[1]) + (ws[2] + ws[3])) / NPIX);
}

extern "C" void kernel_launch(void* const* d_in, const int* in_sizes, int n_in,
                              void* d_out, int out_size, void* d_ws, size_t ws_size,
                              hipStream_t stream) {
    const float* img1 = (const float*)d_in[0];
    const float* img2 = (const float*)d_in[1];
    float* out = (float*)d_out;

    // Gaussian window (host, double precision, normalized)
    GaussW gw;
    {
        double g[11], sum = 0.0;
        for (int i = 0; i < 11; ++i) {
            const double c = (double)(i - 5);
            g[i] = std::exp(-(c * c) / 4.5);   // 2*sigma^2 = 4.5
            sum += g[i];
        }
        for (int i = 0; i < 11; ++i) gw.w[i] = (float)(g[i] / sum);
    }

    dim3 grid(IMG_W / TW, IMG_H / TH, NPLANES);   // 8 x 16 x 96 = 12288
    const int nPart = grid.x * grid.y * grid.z;

    if (ws_size >= (size_t)nPart * sizeof(float)) {
        // deterministic two-stage reduction
        ssim_main<<<grid, 256, 0, stream>>>(img1, img2, (float*)d_ws, gw, 0, out);
        ssim_reduce<<<1, 256, 0, stream>>>((float*)d_ws, nPart, out);
    } else {
        // fallback: atomic accumulation (still within tolerance)
        hipMemsetAsync(d_out, 0, sizeof(float), stream);
        ssim_main<<<grid, 256, 0, stream>>>(img1, img2, nullptr, gw, 1, out);
    }
}